// Round 6
// baseline (1062.628 us; speedup 1.0000x reference)
//
#include <hip/hip_runtime.h>
#include <math.h>

#define NN 50000
#define NE 400000
#define RSQRT32 0.17677669529663687f

typedef __attribute__((ext_vector_type(8))) short bf16x8;
typedef __attribute__((ext_vector_type(4))) float f32x4;
#define MFMA_B16(a, b, c) __builtin_amdgcn_mfma_f32_16x16x32_bf16(a, b, c, 0, 0, 0)

// ---------------- workspace layout (bytes) ----------------
#define O_FLAG  0ULL
#define O_BSUM  256ULL                         // 196 ints (scan block sums)
#define O_SRCI  1280ULL                        // E*4
#define O_DSTI  (O_SRCI + 1600000ULL)          // E*4 -> s1 alias after scatter
#define O_DEG   (O_DSTI + 1600000ULL)          // N*4
#define O_CUR   (O_DEG + 200192ULL)            // N*4 -> s2 alias
#define O_START (O_CUR + 200192ULL)            // (N+1)*4
#define O_SRCS  (O_START + 200704ULL)          // E*4
#define O_ORIG  (O_SRCS + 1600000ULL)          // E*4
#define O_RELT  (O_ORIG + 1600000ULL)          // E*4
#define O_Q1    (O_RELT + 1600000ULL)          // N*256*2 bf16; later Q2/K2/V2/S2m fp32
#define O_K1    (O_Q1 + 25600000ULL)           // bf16; later G2 fp32
#define O_V1    (O_K1 + 25600000ULL)           // bf16; later h bf16
#define O_S1M   (O_V1 + 25600000ULL)           // bf16; later A2 fp32
#define O_G1    (O_S1M + 25600000ULL)          // N*1024*2 bf16; A1 aliases exactly; later numv2
#define O_WB1   (O_G1 + 102400000ULL)          // [4][256][128] bf16
#define O_WG1   (O_WB1 + 262144ULL)            // [8][128][32] bf16
#define O_WF1   (O_WG1 + 65536ULL)             // [8][32][128] bf16
#define O_WB2   (O_WF1 + 65536ULL)             // [128][256] bf16
#define O_NUMV1 (O_WB2 + 65536ULL)             // N*256*4 fp32 (dedicated: Q1/K1 live during agg)
#define WS_TOTAL (O_NUMV1 + 51200000ULL)
// aliases
#define O_S1    O_DSTI                         // N*8*4
#define O_A1    O_G1                           // N*1024*2 bf16 (exact overlay of G1)
#define O_H     O_V1                           // N*256*2 bf16
#define O_Q2    O_Q1                           // N*32*4 fp32
#define O_K2    (O_Q1 + 6400000ULL)
#define O_V2    (O_Q1 + 12800000ULL)
#define O_S2M   (O_Q1 + 19200000ULL)
#define O_G2    O_K1                           // N*128*4 fp32
#define O_A2    O_S1M                          // N*128*4 fp32
#define O_NUMV2 O_G1                           // N*32*4 fp32
#define O_S2    O_CUR                          // N*4

__device__ __forceinline__ unsigned short f2bf(float f) {
    unsigned int u = __float_as_uint(f);
    unsigned int r = (u + 0x7fffu + ((u >> 16) & 1u)) >> 16;
    return (unsigned short)r;
}
__device__ __forceinline__ float bf2f(unsigned short u) {
    return __uint_as_float(((unsigned int)u) << 16);
}
__device__ __forceinline__ float4 ld_bf16x4(const unsigned short* p) {
    const ushort4 u = *(const ushort4*)p;
    float4 r;
    r.x = bf2f(u.x); r.y = bf2f(u.y); r.z = bf2f(u.z); r.w = bf2f(u.w);
    return r;
}
__device__ __forceinline__ ushort4 st_bf16x4(float a, float b, float c, float d) {
    ushort4 u; u.x = f2bf(a); u.y = f2bf(b); u.z = f2bf(c); u.w = f2bf(d);
    return u;
}

// ---------------- index dtype detect ----------------
__global__ void k_detect(const unsigned int* ei, int* flag) {
    if (threadIdx.x == 0) {
        int is64 = 1;
        for (int i = 0; i < 64; ++i)
            if (ei[2 * i + 1] != 0u) { is64 = 0; break; }
        *flag = is64;
    }
}

// ---------------- convert + degree histogram (fused) ----------------
__global__ void k_convhist(const void* ei, const int* flag,
                           int* __restrict__ srcI, int* __restrict__ dstI,
                           int* __restrict__ deg) {
    int i = blockIdx.x * 256 + threadIdx.x;
    if (i >= NE) return;
    int s, d;
    if (*flag) {
        const long long* p = (const long long*)ei;
        s = (int)p[i]; d = (int)p[NE + i];
    } else {
        const int* p = (const int*)ei;
        s = p[i]; d = p[NE + i];
    }
    srcI[i] = s;
    dstI[i] = d;
    atomicAdd(&deg[d], 1);
}

// ---------------- parallel 3-phase exclusive scan over deg ----------------
__global__ void k_scanA(const int* __restrict__ deg, int* __restrict__ locs,
                        int* __restrict__ bsum) {
    __shared__ int sm[256];
    const int t = threadIdx.x;
    const int gidx = blockIdx.x * 256 + t;
    int v = (gidx < NN) ? deg[gidx] : 0;
    sm[t] = v;
    __syncthreads();
    for (int off = 1; off < 256; off <<= 1) {
        int u = (t >= off) ? sm[t - off] : 0;
        __syncthreads();
        sm[t] += u;
        __syncthreads();
    }
    if (gidx < NN) locs[gidx] = sm[t];          // inclusive local scan
    if (t == 255) bsum[blockIdx.x] = sm[255];
}

__global__ void k_scanB(int* __restrict__ bsum) {
    __shared__ int sm[256];
    const int t = threadIdx.x;
    int v = (t < 196) ? bsum[t] : 0;
    sm[t] = v;
    __syncthreads();
    for (int off = 1; off < 256; off <<= 1) {
        int u = (t >= off) ? sm[t - off] : 0;
        __syncthreads();
        sm[t] += u;
        __syncthreads();
    }
    if (t < 196) bsum[t] = sm[t] - v;           // exclusive block offsets
}

__global__ void k_scanC(const int* __restrict__ deg, const int* __restrict__ bsum,
                        int* __restrict__ startA, int* __restrict__ cursor) {
    const int t = threadIdx.x;
    const int gidx = blockIdx.x * 256 + t;
    if (gidx < NN) {
        const int ex = startA[gidx] - deg[gidx] + bsum[blockIdx.x];
        startA[gidx] = ex;
        cursor[gidx] = ex;
    }
    if (gidx == 0) startA[NN] = NE;
}

__global__ void k_scatter(const int* __restrict__ srcI, const int* __restrict__ dstI,
                          const float* __restrict__ lu, const float* __restrict__ tE,
                          int* __restrict__ cursor,
                          int* __restrict__ srcS, int* __restrict__ orig,
                          float* __restrict__ relT) {
    int i = blockIdx.x * 256 + threadIdx.x;
    if (i >= NE) return;
    const int d = dstI[i];
    const int s = srcI[i];
    const int pos = atomicAdd(&cursor[d], 1);
    srcS[pos] = s;
    orig[pos] = i;
    relT[pos] = lu[s] - tE[i];
}

// ---------------- weight prep: pack bf16 B^T forms ----------------
__global__ void k_prepw(
    const float* __restrict__ Wq1, const float* __restrict__ Wk1,
    const float* __restrict__ Wv1, const float* __restrict__ Ws1,
    const float* __restrict__ We1,
    const float* __restrict__ Wq2, const float* __restrict__ Wk2,
    const float* __restrict__ Wv2, const float* __restrict__ Ws2,
    unsigned short* __restrict__ WB1, unsigned short* __restrict__ WG1,
    unsigned short* __restrict__ WF1, unsigned short* __restrict__ WB2)
{
    const int i = blockIdx.x * 256 + threadIdx.x;
    if (i < 131072) {                       // WB1[part][n 256][k 128]
        const int part = i >> 15;
        const int rem = i & 32767;
        const int n = rem >> 7, k = rem & 127;
        const float* W = part == 0 ? Wq1 : part == 1 ? Wk1 : part == 2 ? Wv1 : Ws1;
        WB1[i] = f2bf(W[(size_t)k * 256 + n]);
    } else if (i < 163840) {                // WG1[h][ko 128][c 32]
        const int j = i - 131072;
        const int h = j >> 12, ko = (j >> 5) & 127, c = j & 31;
        WG1[j] = f2bf(We1[(size_t)ko * 256 + h * 32 + c]);
    } else if (i < 196608) {                // WF1[h][c 32][ko 128]
        const int j = i - 163840;
        const int h = j >> 12, c = (j >> 7) & 31, ko = j & 127;
        WF1[j] = f2bf(We1[(size_t)ko * 256 + h * 32 + c]);
    } else if (i < 229376) {                // WB2[col 128][k 256]
        const int j = i - 196608;
        const int col = j >> 8, k = j & 255;
        const int part = col >> 5, pc = col & 31;
        const float* W = part == 0 ? Wq2 : part == 1 ? Wk2 : part == 2 ? Wv2 : Ws2;
        WB2[j] = f2bf(W[(size_t)k * 32 + pc]);
    }
}

// ---------------- MFMA node GEMM layer 1 ----------------
__global__ __launch_bounds__(256) void k_gemm1m(
    const float* __restrict__ x, const unsigned short* __restrict__ WB1,
    const float* __restrict__ c0, const float* __restrict__ c1,
    const float* __restrict__ c2, const float* __restrict__ c3,
    unsigned short* __restrict__ Q1b, unsigned short* __restrict__ K1b,
    unsigned short* __restrict__ V1b, unsigned short* __restrict__ S1mb)
{
    __shared__ unsigned short As[64 * 136];
    __shared__ unsigned short Bs[64 * 136];
    const int t = threadIdx.x;
    const int row0 = blockIdx.x * 64;
    const int by = blockIdx.y;
    const int part = by >> 2;
    const int pcol0 = (by & 3) * 64;
    const float* bp = part == 0 ? c0 : part == 1 ? c1 : part == 2 ? c2 : c3;
    unsigned short* Ob = part == 0 ? Q1b : part == 1 ? K1b : part == 2 ? V1b : S1mb;

    {
        const int r = t >> 2, cc = (t & 3) * 32;
        const int gr = row0 + r;
        unsigned short* dst = As + r * 136 + cc;
        if (gr < NN) {
            const float4* xp = (const float4*)(x + (size_t)gr * 128 + cc);
            #pragma unroll
            for (int i = 0; i < 8; ++i) {
                const float4 v = xp[i];
                *(ushort4*)(dst + 4 * i) = st_bf16x4(v.x, v.y, v.z, v.w);
            }
        } else {
            const ushort4 z = {0, 0, 0, 0};
            #pragma unroll
            for (int i = 0; i < 8; ++i) *(ushort4*)(dst + 4 * i) = z;
        }
    }
    {
        const int n = t >> 2, kk = (t & 3) * 32;
        const unsigned short* src = WB1 + ((size_t)part * 256 + pcol0 + n) * 128 + kk;
        unsigned short* dst = Bs + n * 136 + kk;
        #pragma unroll
        for (int i = 0; i < 4; ++i)
            *(bf16x8*)(dst + 8 * i) = *(const bf16x8*)(src + 8 * i);
    }
    __syncthreads();

    const int w = t >> 6, lane = t & 63, m = lane & 15, quad = lane >> 4;
    f32x4 acc[4];
    #pragma unroll
    for (int i = 0; i < 4; ++i) acc[i] = (f32x4){0.f, 0.f, 0.f, 0.f};
    #pragma unroll
    for (int kc = 0; kc < 4; ++kc) {
        const bf16x8 af = *(const bf16x8*)(As + (16 * w + m) * 136 + kc * 32 + quad * 8);
        #pragma unroll
        for (int ct = 0; ct < 4; ++ct) {
            const bf16x8 bf = *(const bf16x8*)(Bs + (16 * ct + m) * 136 + kc * 32 + quad * 8);
            acc[ct] = MFMA_B16(af, bf, acc[ct]);
        }
    }
    #pragma unroll
    for (int ct = 0; ct < 4; ++ct) {
        const int colp = pcol0 + ct * 16 + m;
        const float b = bp[colp];
        #pragma unroll
        for (int r = 0; r < 4; ++r) {
            const int gr = row0 + 16 * w + quad * 4 + r;
            if (gr < NN) Ob[(size_t)gr * 256 + colp] = f2bf(acc[ct][r] + b);
        }
    }
}

// ---------------- MFMA G1 ----------------
__global__ __launch_bounds__(256) void k_g1m(
    const unsigned short* __restrict__ Q1b, const unsigned short* __restrict__ WG1,
    unsigned short* __restrict__ G1b)
{
    __shared__ unsigned short As[64 * 40];
    __shared__ unsigned short Bs[128 * 40];
    const int t = threadIdx.x;
    const int n0 = blockIdx.x * 64;
    const int h = blockIdx.y;
    {
        const int n = t >> 2, c = (t & 3) * 8;
        const int gn = n0 + n;
        bf16x8 v = {};
        if (gn < NN) v = *(const bf16x8*)(Q1b + (size_t)gn * 256 + h * 32 + c);
        *(bf16x8*)(As + n * 40 + c) = v;
    }
    {
        const int ko = t >> 1, c = (t & 1) * 16;
        const unsigned short* src = WG1 + (size_t)h * 4096 + ko * 32 + c;
        *(bf16x8*)(Bs + ko * 40 + c) = *(const bf16x8*)(src);
        *(bf16x8*)(Bs + ko * 40 + c + 8) = *(const bf16x8*)(src + 8);
    }
    __syncthreads();

    const int w = t >> 6, lane = t & 63, m = lane & 15, quad = lane >> 4;
    f32x4 acc[8];
    #pragma unroll
    for (int i = 0; i < 8; ++i) acc[i] = (f32x4){0.f, 0.f, 0.f, 0.f};
    const bf16x8 af = *(const bf16x8*)(As + (16 * w + m) * 40 + quad * 8);
    #pragma unroll
    for (int ct = 0; ct < 8; ++ct) {
        const bf16x8 bf = *(const bf16x8*)(Bs + (16 * ct + m) * 40 + quad * 8);
        acc[ct] = MFMA_B16(af, bf, acc[ct]);
    }
    #pragma unroll
    for (int ct = 0; ct < 8; ++ct) {
        const int k = ct * 16 + m;
        #pragma unroll
        for (int r = 0; r < 4; ++r) {
            const int gn = n0 + 16 * w + quad * 4 + r;
            if (gn < NN) G1b[(size_t)gn * 1024 + h * 128 + k] = f2bf(acc[ct][r]);
        }
    }
}

// ---------------- G2 (fp32) ----------------
__global__ __launch_bounds__(256) void k_g2(
    const float* __restrict__ Q2, const float* __restrict__ We2,
    float* __restrict__ G2)
{
    __shared__ float Qs[64][36];
    __shared__ float Ws[128][36];
    const int t = threadIdx.x;
    const int n0 = blockIdx.x * 64;
    {
        const int n = t >> 2, c8 = (t & 3) * 8;
        float4 v0 = make_float4(0.f,0.f,0.f,0.f), v1 = v0;
        if (n0 + n < NN) {
            v0 = *(const float4*)(Q2 + (size_t)(n0 + n) * 32 + c8);
            v1 = *(const float4*)(Q2 + (size_t)(n0 + n) * 32 + c8 + 4);
        }
        *(float4*)(&Qs[n][c8]) = v0;
        *(float4*)(&Qs[n][c8 + 4]) = v1;
    }
    {
        const int k = t >> 1, c16 = (t & 1) * 16;
        #pragma unroll
        for (int i = 0; i < 4; ++i)
            *(float4*)(&Ws[k][c16 + 4 * i]) =
                *(const float4*)(We2 + (size_t)k * 32 + c16 + 4 * i);
    }
    __syncthreads();
    const int tx = t & 15, ty = t >> 4;
    const int k8 = tx * 8, n4 = ty * 4;
    float acc[4][8] = {};
    #pragma unroll 8
    for (int c = 0; c < 32; ++c) {
        float a[4], b[8];
        #pragma unroll
        for (int i = 0; i < 4; ++i) a[i] = Qs[n4 + i][c];
        #pragma unroll
        for (int j = 0; j < 8; ++j) b[j] = Ws[k8 + j][c];
        #pragma unroll
        for (int i = 0; i < 4; ++i)
            #pragma unroll
            for (int j = 0; j < 8; ++j)
                acc[i][j] += a[i] * b[j];
    }
    #pragma unroll
    for (int i = 0; i < 4; ++i) {
        const int gn = n0 + n4 + i;
        if (gn < NN) {
            float* gp = G2 + (size_t)gn * 128 + k8;
            *(float4*)(gp)     = make_float4(acc[i][0], acc[i][1], acc[i][2], acc[i][3]);
            *(float4*)(gp + 4) = make_float4(acc[i][4], acc[i][5], acc[i][6], acc[i][7]);
        }
    }
}

// ---------------- FUSED layer-1 attention + aggregation, 2x unrolled ----------
// block = 8 dsts x 32 lanes. Edge loop unrolled x2: two independent
// logit/butterfly/exp chains in flight per dst-group (4 per wave) to raise MLP.
__global__ __launch_bounds__(256, 4) void k_agg1(
    const int* __restrict__ startA, const int* __restrict__ srcS,
    const int* __restrict__ orig, const float* __restrict__ relT,
    const float* __restrict__ msg, const float* __restrict__ tw,
    const float* __restrict__ tb,
    const unsigned short* __restrict__ Q1b, const unsigned short* __restrict__ K1b,
    const unsigned short* __restrict__ V1b, const unsigned short* G1b,
    unsigned short* A1b, float* __restrict__ numv1, float* __restrict__ s1)
{
    const int t = threadIdx.x;
    const int g = t >> 5, l = t & 31;
    const int lane64 = t & 63;
    const int d = blockIdx.x * 8 + g;
    const int eb = startA[d], ee = startA[d + 1];
    const int hl = l >> 2;

    float q8[8];
    {
        const unsigned short* qp = Q1b + (size_t)d * 256 + l * 8;
        const float4 q0 = ld_bf16x4(qp), q1 = ld_bf16x4(qp + 4);
        q8[0]=q0.x; q8[1]=q0.y; q8[2]=q0.z; q8[3]=q0.w;
        q8[4]=q1.x; q8[5]=q1.y; q8[6]=q1.z; q8[7]=q1.w;
    }
    float gv[8][4];
    #pragma unroll
    for (int h = 0; h < 8; ++h) {
        const float4 gg = ld_bf16x4(G1b + (size_t)d * 1024 + h * 128 + l * 4);
        gv[h][0]=gg.x; gv[h][1]=gg.y; gv[h][2]=gg.z; gv[h][3]=gg.w;
    }
    float4 twl = make_float4(0.f,0.f,0.f,0.f), tbl = twl;
    if (l < 16) {
        twl = *(const float4*)(tw + l * 4);
        tbl = *(const float4*)(tb + l * 4);
    }

    float a1acc[8][4] = {};
    float nv[8] = {};
    float sacc = 0.f;

    int e = eb;
    for (; e + 2 <= ee; e += 2) {
        const int s0 = srcS[e], s1i = srcS[e + 1];
        float a0[4], a1[4];
        if (l < 16) {
            const float rt0 = relT[e], rt1 = relT[e + 1];
            a0[0] = __cosf(rt0 * twl.x + tbl.x);
            a0[1] = __cosf(rt0 * twl.y + tbl.y);
            a0[2] = __cosf(rt0 * twl.z + tbl.z);
            a0[3] = __cosf(rt0 * twl.w + tbl.w);
            a1[0] = __cosf(rt1 * twl.x + tbl.x);
            a1[1] = __cosf(rt1 * twl.y + tbl.y);
            a1[2] = __cosf(rt1 * twl.z + tbl.z);
            a1[3] = __cosf(rt1 * twl.w + tbl.w);
        } else {
            const float4 m0 = *(const float4*)(msg + (size_t)orig[e] * 64 + (l - 16) * 4);
            const float4 m1 = *(const float4*)(msg + (size_t)orig[e + 1] * 64 + (l - 16) * 4);
            a0[0]=m0.x; a0[1]=m0.y; a0[2]=m0.z; a0[3]=m0.w;
            a1[0]=m1.x; a1[1]=m1.y; a1[2]=m1.z; a1[3]=m1.w;
        }
        float p0[8], p1[8];
        #pragma unroll
        for (int h = 0; h < 8; ++h) {
            p0[h] = a0[0]*gv[h][0] + a0[1]*gv[h][1] + a0[2]*gv[h][2] + a0[3]*gv[h][3];
            p1[h] = a1[0]*gv[h][0] + a1[1]*gv[h][1] + a1[2]*gv[h][2] + a1[3]*gv[h][3];
        }
        {
            const unsigned short* kp0 = K1b + (size_t)s0 * 256 + l * 8;
            const unsigned short* kp1 = K1b + (size_t)s1i * 256 + l * 8;
            const float4 k00 = ld_bf16x4(kp0), k01 = ld_bf16x4(kp0 + 4);
            const float4 k10 = ld_bf16x4(kp1), k11 = ld_bf16x4(kp1 + 4);
            p0[hl] += q8[0]*k00.x + q8[1]*k00.y + q8[2]*k00.z + q8[3]*k00.w
                    + q8[4]*k01.x + q8[5]*k01.y + q8[6]*k01.z + q8[7]*k01.w;
            p1[hl] += q8[0]*k10.x + q8[1]*k10.y + q8[2]*k10.z + q8[3]*k10.w
                    + q8[4]*k11.x + q8[5]*k11.y + q8[6]*k11.z + q8[7]*k11.w;
        }
        #pragma unroll
        for (int mk = 1; mk < 32; mk <<= 1) {
            #pragma unroll
            for (int h = 0; h < 8; ++h) {
                p0[h] += __shfl_xor(p0[h], mk);
                p1[h] += __shfl_xor(p1[h], mk);
            }
        }
        const float pe0 = __expf(fminf(p0[lane64 & 7] * RSQRT32, 80.f));
        const float pe1 = __expf(fminf(p1[lane64 & 7] * RSQRT32, 80.f));
        float pa0[8], pa1[8];
        #pragma unroll
        for (int h = 0; h < 8; ++h) {
            pa0[h] = __shfl(pe0, (lane64 & 32) + h);
            pa1[h] = __shfl(pe1, (lane64 & 32) + h);
        }
        #pragma unroll
        for (int h = 0; h < 8; ++h) {
            a1acc[h][0] += pa0[h]*a0[0] + pa1[h]*a1[0];
            a1acc[h][1] += pa0[h]*a0[1] + pa1[h]*a1[1];
            a1acc[h][2] += pa0[h]*a0[2] + pa1[h]*a1[2];
            a1acc[h][3] += pa0[h]*a0[3] + pa1[h]*a1[3];
        }
        {
            const unsigned short* vp0 = V1b + (size_t)s0 * 256 + l * 8;
            const unsigned short* vp1 = V1b + (size_t)s1i * 256 + l * 8;
            const float4 v00 = ld_bf16x4(vp0), v01 = ld_bf16x4(vp0 + 4);
            const float4 v10 = ld_bf16x4(vp1), v11 = ld_bf16x4(vp1 + 4);
            const float pv0 = pa0[hl], pv1 = pa1[hl];
            nv[0] += pv0*v00.x + pv1*v10.x; nv[1] += pv0*v00.y + pv1*v10.y;
            nv[2] += pv0*v00.z + pv1*v10.z; nv[3] += pv0*v00.w + pv1*v10.w;
            nv[4] += pv0*v01.x + pv1*v11.x; nv[5] += pv0*v01.y + pv1*v11.y;
            nv[6] += pv0*v01.z + pv1*v11.z; nv[7] += pv0*v01.w + pv1*v11.w;
            sacc += pv0 + pv1;
        }
    }
    if (e < ee) {   // tail edge
        const int s = srcS[e];
        float a[4];
        if (l < 16) {
            const float rt = relT[e];
            a[0] = __cosf(rt * twl.x + tbl.x);
            a[1] = __cosf(rt * twl.y + tbl.y);
            a[2] = __cosf(rt * twl.z + tbl.z);
            a[3] = __cosf(rt * twl.w + tbl.w);
        } else {
            const float4 m4 = *(const float4*)(msg + (size_t)orig[e] * 64 + (l - 16) * 4);
            a[0]=m4.x; a[1]=m4.y; a[2]=m4.z; a[3]=m4.w;
        }
        float part[8];
        #pragma unroll
        for (int h = 0; h < 8; ++h)
            part[h] = a[0]*gv[h][0] + a[1]*gv[h][1] + a[2]*gv[h][2] + a[3]*gv[h][3];
        {
            const unsigned short* kp = K1b + (size_t)s * 256 + l * 8;
            const float4 k0 = ld_bf16x4(kp), k1 = ld_bf16x4(kp + 4);
            part[hl] += q8[0]*k0.x + q8[1]*k0.y + q8[2]*k0.z + q8[3]*k0.w
                      + q8[4]*k1.x + q8[5]*k1.y + q8[6]*k1.z + q8[7]*k1.w;
        }
        #pragma unroll
        for (int mk = 1; mk < 32; mk <<= 1) {
            #pragma unroll
            for (int h = 0; h < 8; ++h)
                part[h] += __shfl_xor(part[h], mk);
        }
        const float pe = __expf(fminf(part[lane64 & 7] * RSQRT32, 80.f));
        float p_all[8];
        #pragma unroll
        for (int h = 0; h < 8; ++h)
            p_all[h] = __shfl(pe, (lane64 & 32) + h);
        #pragma unroll
        for (int h = 0; h < 8; ++h) {
            a1acc[h][0] += p_all[h]*a[0]; a1acc[h][1] += p_all[h]*a[1];
            a1acc[h][2] += p_all[h]*a[2]; a1acc[h][3] += p_all[h]*a[3];
        }
        {
            const unsigned short* vp = V1b + (size_t)s * 256 + l * 8;
            const float4 v0 = ld_bf16x4(vp), v1 = ld_bf16x4(vp + 4);
            const float pv = p_all[hl];
            nv[0] += pv*v0.x; nv[1] += pv*v0.y; nv[2] += pv*v0.z; nv[3] += pv*v0.w;
            nv[4] += pv*v1.x; nv[5] += pv*v1.y; nv[6] += pv*v1.z; nv[7] += pv*v1.w;
            sacc += pv;
        }
    }
    #pragma unroll
    for (int h = 0; h < 8; ++h)
        *(ushort4*)(A1b + (size_t)d * 1024 + h * 128 + l * 4) =
            st_bf16x4(a1acc[h][0], a1acc[h][1], a1acc[h][2], a1acc[h][3]);
    float* np = numv1 + (size_t)d * 256 + l * 8;
    *(float4*)(np)     = make_float4(nv[0], nv[1], nv[2], nv[3]);
    *(float4*)(np + 4) = make_float4(nv[4], nv[5], nv[6], nv[7]);
    if ((l & 3) == 0) s1[(size_t)d * 8 + hl] = sacc;
}

// ---------------- MFMA fold layer 1 ----------------
__global__ __launch_bounds__(256) void k_foldC1m(
    const unsigned short* __restrict__ A1b, const unsigned short* __restrict__ WF1,
    const float* __restrict__ numv1, const float* __restrict__ s1,
    const unsigned short* __restrict__ S1mb, unsigned short* __restrict__ hb)
{
    __shared__ unsigned short As[64 * 136];
    __shared__ unsigned short Bs[32 * 136];
    const int t = threadIdx.x;
    const int n0 = blockIdx.x * 64;
    const int h = blockIdx.y;
    {
        const int n = t >> 2, kk = (t & 3) * 32;
        const int gn = n0 + n;
        unsigned short* dst = As + n * 136 + kk;
        if (gn < NN) {
            const unsigned short* src = A1b + (size_t)gn * 1024 + h * 128 + kk;
            #pragma unroll
            for (int i = 0; i < 4; ++i)
                *(bf16x8*)(dst + 8 * i) = *(const bf16x8*)(src + 8 * i);
        } else {
            const bf16x8 z = {};
            #pragma unroll
            for (int i = 0; i < 4; ++i) *(bf16x8*)(dst + 8 * i) = z;
        }
    }
    {
        const int c = t >> 3, kk = (t & 7) * 16;
        const unsigned short* src = WF1 + (size_t)h * 4096 + c * 128 + kk;
        *(bf16x8*)(Bs + c * 136 + kk) = *(const bf16x8*)(src);
        *(bf16x8*)(Bs + c * 136 + kk + 8) = *(const bf16x8*)(src + 8);
    }
    __syncthreads();

    const int w = t >> 6, lane = t & 63, m = lane & 15, quad = lane >> 4;
    f32x4 acc[2];
    acc[0] = (f32x4){0.f, 0.f, 0.f, 0.f};
    acc[1] = (f32x4){0.f, 0.f, 0.f, 0.f};
    #pragma unroll
    for (int kc = 0; kc < 4; ++kc) {
        const bf16x8 af = *(const bf16x8*)(As + (16 * w + m) * 136 + kc * 32 + quad * 8);
        #pragma unroll
        for (int ct = 0; ct < 2; ++ct) {
            const bf16x8 bf = *(const bf16x8*)(Bs + (16 * ct + m) * 136 + kc * 32 + quad * 8);
            acc[ct] = MFMA_B16(af, bf, acc[ct]);
        }
    }
    #pragma unroll
    for (int ct = 0; ct < 2; ++ct) {
        const int c = ct * 16 + m;
        #pragma unroll
        for (int r = 0; r < 4; ++r) {
            const int gn = n0 + 16 * w + quad * 4 + r;
            if (gn < NN) {
                const float s = s1[(size_t)gn * 8 + h] + 1e-16f;
                const float nvv = numv1[(size_t)gn * 256 + h * 32 + c];
                const float sk = bf2f(S1mb[(size_t)gn * 256 + h * 32 + c]);
                float v = (acc[ct][r] + nvv) / s + sk;
                v = v > 0.f ? v : 0.f;
                hb[(size_t)gn * 256 + h * 32 + c] = f2bf(v);
            }
        }
    }
}

// ---------------- MFMA node GEMM layer 2 ----------------
__global__ __launch_bounds__(256) void k_gemm2m(
    const unsigned short* __restrict__ hb, const unsigned short* __restrict__ WB2,
    const float* __restrict__ c0, const float* __restrict__ c1,
    const float* __restrict__ c2, const float* __restrict__ c3,
    float* __restrict__ O0, float* __restrict__ O1,
    float* __restrict__ O2, float* __restrict__ O3)
{
    __shared__ unsigned short As[64 * 136];
    __shared__ unsigned short Bs[64 * 136];
    const int t = threadIdx.x;
    const int row0 = blockIdx.x * 64;
    const int coly = blockIdx.y;
    const int w = t >> 6, lane = t & 63, m = lane & 15, quad = lane >> 4;

    f32x4 acc[4];
    #pragma unroll
    for (int i = 0; i < 4; ++i) acc[i] = (f32x4){0.f, 0.f, 0.f, 0.f};

    for (int kb = 0; kb < 2; ++kb) {
        if (kb) __syncthreads();
        {
            const int r = t >> 2, kk = (t & 3) * 32;
            const int gr = row0 + r;
            unsigned short* dst = As + r * 136 + kk;
            if (gr < NN) {
                const unsigned short* src = hb + (size_t)gr * 256 + kb * 128 + kk;
                #pragma unroll
                for (int i = 0; i < 4; ++i)
                    *(bf16x8*)(dst + 8 * i) = *(const bf16x8*)(src + 8 * i);
            } else {
                const bf16x8 z = {};
                #pragma unroll
                for (int i = 0; i < 4; ++i) *(bf16x8*)(dst + 8 * i) = z;
            }
        }
        {
            const int n = t >> 2, kk = (t & 3) * 32;
            const unsigned short* src = WB2 + (size_t)(coly * 64 + n) * 256 + kb * 128 + kk;
            unsigned short* dst = Bs + n * 136 + kk;
            #pragma unroll
            for (int i = 0; i < 4; ++i)
                *(bf16x8*)(dst + 8 * i) = *(const bf16x8*)(src + 8 * i);
        }
        __syncthreads();
        #pragma unroll
        for (int kc = 0; kc < 4; ++kc) {
            const bf16x8 af = *(const bf16x8*)(As + (16 * w + m) * 136 + kc * 32 + quad * 8);
            #pragma unroll
            for (int ct = 0; ct < 4; ++ct) {
                const bf16x8 bf = *(const bf16x8*)(Bs + (16 * ct + m) * 136 + kc * 32 + quad * 8);
                acc[ct] = MFMA_B16(af, bf, acc[ct]);
            }
        }
    }
    #pragma unroll
    for (int ct = 0; ct < 4; ++ct) {
        const int col = coly * 64 + ct * 16 + m;
        const int part = col >> 5, pc = col & 31;
        const float* bb = part == 0 ? c0 : part == 1 ? c1 : part == 2 ? c2 : c3;
        float* Op = part == 0 ? O0 : part == 1 ? O1 : part == 2 ? O2 : O3;
        const float b = bb[pc];
        #pragma unroll
        for (int r = 0; r < 4; ++r) {
            const int gr = row0 + 16 * w + quad * 4 + r;
            if (gr < NN) Op[(size_t)gr * 32 + pc] = acc[ct][r] + b;
        }
    }
}

// ---------------- layer 2 fused p + aggregate, 2x unrolled ----------------
__global__ __launch_bounds__(256) void k_aggB2(
    const int* __restrict__ startA, const int* __restrict__ srcS,
    const int* __restrict__ orig, const float* __restrict__ relT,
    const float* __restrict__ msg, const float* __restrict__ tw,
    const float* __restrict__ tb,
    const float* __restrict__ Q2, const float* __restrict__ K2,
    const float* __restrict__ V2, const float* __restrict__ G2,
    float* __restrict__ A2, float* __restrict__ numv2, float* __restrict__ s2)
{
    const int t = threadIdx.x;
    const int g = t >> 5, l = t & 31;
    const int d = blockIdx.x * 8 + g;
    const int eb = startA[d], ee = startA[d + 1];

    const float q2l = Q2[(size_t)d * 32 + l];
    const float4 g2l = *(const float4*)(G2 + (size_t)d * 128 + l * 4);
    float4 twl = make_float4(0.f,0.f,0.f,0.f), tbl = twl;
    if (l < 16) {
        twl = *(const float4*)(tw + l * 4);
        tbl = *(const float4*)(tb + l * 4);
    }
    float acc2[4] = {};
    float nvacc = 0.f, sacc = 0.f;

    int e = eb;
    for (; e + 2 <= ee; e += 2) {
        const int s0 = srcS[e], s1i = srcS[e + 1];
        float a0[4], a1[4];
        if (l < 16) {
            const float rt0 = relT[e], rt1 = relT[e + 1];
            a0[0] = __cosf(rt0 * twl.x + tbl.x);
            a0[1] = __cosf(rt0 * twl.y + tbl.y);
            a0[2] = __cosf(rt0 * twl.z + tbl.z);
            a0[3] = __cosf(rt0 * twl.w + tbl.w);
            a1[0] = __cosf(rt1 * twl.x + tbl.x);
            a1[1] = __cosf(rt1 * twl.y + tbl.y);
            a1[2] = __cosf(rt1 * twl.z + tbl.z);
            a1[3] = __cosf(rt1 * twl.w + tbl.w);
        } else {
            const float4 m0 = *(const float4*)(msg + (size_t)orig[e] * 64 + (l - 16) * 4);
            const float4 m1 = *(const float4*)(msg + (size_t)orig[e + 1] * 64 + (l - 16) * 4);
            a0[0]=m0.x; a0[1]=m0.y; a0[2]=m0.z; a0[3]=m0.w;
            a1[0]=m1.x; a1[1]=m1.y; a1[2]=m1.z; a1[3]=m1.w;
        }
        float p0 = q2l * K2[(size_t)s0 * 32 + l]
                 + a0[0]*g2l.x + a0[1]*g2l.y + a0[2]*g2l.z + a0[3]*g2l.w;
        float p1 = q2l * K2[(size_t)s1i * 32 + l]
                 + a1[0]*g2l.x + a1[1]*g2l.y + a1[2]*g2l.z + a1[3]*g2l.w;
        #pragma unroll
        for (int mk = 1; mk < 32; mk <<= 1) {
            p0 += __shfl_xor(p0, mk);
            p1 += __shfl_xor(p1, mk);
        }
        const float pw0 = __expf(fminf(p0 * RSQRT32, 80.f));
        const float pw1 = __expf(fminf(p1 * RSQRT32, 80.f));
        acc2[0] += pw0*a0[0] + pw1*a1[0]; acc2[1] += pw0*a0[1] + pw1*a1[1];
        acc2[2] += pw0*a0[2] + pw1*a1[2]; acc2[3] += pw0*a0[3] + pw1*a1[3];
        nvacc += pw0 * V2[(size_t)s0 * 32 + l] + pw1 * V2[(size_t)s1i * 32 + l];
        sacc += pw0 + pw1;
    }
    if (e < ee) {
        const int s = srcS[e];
        float a[4];
        if (l < 16) {
            const float rt = relT[e];
            a[0] = __cosf(rt * twl.x + tbl.x);
            a[1] = __cosf(rt * twl.y + tbl.y);
            a[2] = __cosf(rt * twl.z + tbl.z);
            a[3] = __cosf(rt * twl.w + tbl.w);
        } else {
            const float4 m4 = *(const float4*)(msg + (size_t)orig[e] * 64 + (l - 16) * 4);
            a[0] = m4.x; a[1] = m4.y; a[2] = m4.z; a[3] = m4.w;
        }
        float part = q2l * K2[(size_t)s * 32 + l]
                   + a[0]*g2l.x + a[1]*g2l.y + a[2]*g2l.z + a[3]*g2l.w;
        #pragma unroll
        for (int mk = 1; mk < 32; mk <<= 1) part += __shfl_xor(part, mk);
        const float p = __expf(fminf(part * RSQRT32, 80.f));
        acc2[0] += p*a[0]; acc2[1] += p*a[1]; acc2[2] += p*a[2]; acc2[3] += p*a[3];
        nvacc += p * V2[(size_t)s * 32 + l];
        sacc += p;
    }
    *(float4*)(A2 + (size_t)d * 128 + l * 4) =
        make_float4(acc2[0], acc2[1], acc2[2], acc2[3]);
    numv2[(size_t)d * 32 + l] = nvacc;
    if (l == 0) s2[d] = sacc;
}

// ---------------- fold layer 2 ----------------
__global__ __launch_bounds__(256) void k_foldC2(
    const float* __restrict__ A2, const float* __restrict__ We2,
    const float* __restrict__ numv2, const float* __restrict__ s2,
    const float* __restrict__ S2m, float* __restrict__ out)
{
    __shared__ float Ws[128][36];
    const int t = threadIdx.x;
    {
        const int k = t >> 1, c16 = (t & 1) * 16;
        #pragma unroll
        for (int i = 0; i < 4; ++i)
            *(float4*)(&Ws[k][c16 + 4 * i]) =
                *(const float4*)(We2 + (size_t)k * 32 + c16 + 4 * i);
    }
    __syncthreads();
    const int n = blockIdx.x * 8 + (t >> 5);
    const int c = t & 31;
    const float* ap = A2 + (size_t)n * 128;
    float acc = 0.f;
    #pragma unroll 8
    for (int k = 0; k < 128; k += 4) {
        const float4 a4 = *(const float4*)(ap + k);
        acc += a4.x * Ws[k][c] + a4.y * Ws[k + 1][c] +
               a4.z * Ws[k + 2][c] + a4.w * Ws[k + 3][c];
    }
    const float s = s2[n] + 1e-16f;
    float v = (numv2[(size_t)n * 32 + c] + acc) / s + S2m[(size_t)n * 32 + c];
    out[(size_t)n * 32 + c] = v > 0.f ? v : 0.f;
}

extern "C" void kernel_launch(void* const* d_in, const int* in_sizes, int n_in,
                              void* d_out, int out_size, void* d_ws, size_t ws_size,
                              hipStream_t stream) {
    const float* x   = (const float*)d_in[0];
    const float* lu  = (const float*)d_in[1];
    const void*  ei  = d_in[2];
    const float* tE  = (const float*)d_in[3];
    const float* msg = (const float*)d_in[4];
    const float* tw  = (const float*)d_in[5];
    const float* tb  = (const float*)d_in[6];
    const float* Wq1 = (const float*)d_in[7];  const float* bq1 = (const float*)d_in[8];
    const float* Wk1 = (const float*)d_in[9];  const float* bk1 = (const float*)d_in[10];
    const float* Wv1 = (const float*)d_in[11]; const float* bv1 = (const float*)d_in[12];
    const float* We1 = (const float*)d_in[13];
    const float* Ws1 = (const float*)d_in[14]; const float* bs1 = (const float*)d_in[15];
    const float* Wq2 = (const float*)d_in[16]; const float* bq2 = (const float*)d_in[17];
    const float* Wk2 = (const float*)d_in[18]; const float* bk2 = (const float*)d_in[19];
    const float* Wv2 = (const float*)d_in[20]; const float* bv2 = (const float*)d_in[21];
    const float* We2 = (const float*)d_in[22];
    const float* Ws2 = (const float*)d_in[23]; const float* bs2 = (const float*)d_in[24];
    float* out = (float*)d_out;
    char* ws = (char*)d_ws;

    if (ws_size < WS_TOTAL) return;

    int* flag   = (int*)(ws + O_FLAG);
    int* bsum   = (int*)(ws + O_BSUM);
    int* srcI   = (int*)(ws + O_SRCI);
    int* dstI   = (int*)(ws + O_DSTI);
    int* deg    = (int*)(ws + O_DEG);
    int* cursor = (int*)(ws + O_CUR);
    int* startA = (int*)(ws + O_START);
    int* srcS   = (int*)(ws + O_SRCS);
    int* orig   = (int*)(ws + O_ORIG);
    float* relT = (float*)(ws + O_RELT);
    unsigned short* Q1b  = (unsigned short*)(ws + O_Q1);
    unsigned short* K1b  = (unsigned short*)(ws + O_K1);
    unsigned short* V1b  = (unsigned short*)(ws + O_V1);
    unsigned short* S1mb = (unsigned short*)(ws + O_S1M);
    unsigned short* G1b  = (unsigned short*)(ws + O_G1);
    unsigned short* A1b  = (unsigned short*)(ws + O_A1);   // exact overlay of G1b
    float* numv1 = (float*)(ws + O_NUMV1);
    float* s1    = (float*)(ws + O_S1);
    unsigned short* hb = (unsigned short*)(ws + O_H);
    float* Q2   = (float*)(ws + O_Q2);
    float* K2m  = (float*)(ws + O_K2);
    float* V2m  = (float*)(ws + O_V2);
    float* S2m  = (float*)(ws + O_S2M);
    float* G2   = (float*)(ws + O_G2);
    float* A2   = (float*)(ws + O_A2);
    float* numv2 = (float*)(ws + O_NUMV2);
    float* s2   = (float*)(ws + O_S2);
    unsigned short* WB1 = (unsigned short*)(ws + O_WB1);
    unsigned short* WG1 = (unsigned short*)(ws + O_WG1);
    unsigned short* WF1 = (unsigned short*)(ws + O_WF1);
    unsigned short* WB2 = (unsigned short*)(ws + O_WB2);

    hipMemsetAsync(ws + O_DEG, 0, 200000, stream);

    k_detect<<<1, 64, 0, stream>>>((const unsigned int*)ei, flag);
    k_convhist<<<(NE + 255) / 256, 256, 0, stream>>>(ei, flag, srcI, dstI, deg);
    k_scanA<<<196, 256, 0, stream>>>(deg, startA, bsum);
    k_scanB<<<1, 256, 0, stream>>>(bsum);
    k_scanC<<<196, 256, 0, stream>>>(deg, bsum, startA, cursor);
    k_scatter<<<(NE + 255) / 256, 256, 0, stream>>>(srcI, dstI, lu, tE, cursor,
                                                    srcS, orig, relT);
    k_prepw<<<896, 256, 0, stream>>>(Wq1, Wk1, Wv1, Ws1, We1, Wq2, Wk2, Wv2, Ws2,
                                     WB1, WG1, WF1, WB2);
    k_gemm1m<<<dim3(782, 16), 256, 0, stream>>>(
        x, WB1, bq1, bk1, bv1, bs1, Q1b, K1b, V1b, S1mb);
    k_g1m<<<dim3(782, 8), 256, 0, stream>>>(Q1b, WG1, G1b);
    k_agg1<<<NN / 8, 256, 0, stream>>>(startA, srcS, orig, relT, msg, tw, tb,
                                       Q1b, K1b, V1b, G1b, A1b, numv1, s1);
    k_foldC1m<<<dim3(782, 8), 256, 0, stream>>>(A1b, WF1, numv1, s1, S1mb, hb);
    k_gemm2m<<<dim3(782, 2), 256, 0, stream>>>(
        hb, WB2, bq2, bk2, bv2, bs2, Q2, K2m, V2m, S2m);
    k_g2<<<782, 256, 0, stream>>>(Q2, We2, G2);
    k_aggB2<<<NN / 8, 256, 0, stream>>>(startA, srcS, orig, relT, msg, tw, tb,
                                        Q2, K2m, V2m, G2, A2, numv2, s2);
    k_foldC2<<<NN / 8, 256, 0, stream>>>(A2, We2, numv2, s2, S2m, out);
}